// Round 4
// baseline (344.255 us; speedup 1.0000x reference)
//
#include <hip/hip_runtime.h>
#include <stdint.h>
#include <math.h>

#define DEVI __device__ __forceinline__

typedef __attribute__((ext_vector_type(8))) short bf16x8;
typedef __attribute__((ext_vector_type(4))) float f32x4;

DEVI unsigned short f2bf(float f) {
  union { float f; unsigned u; } v; v.f = f;
  unsigned u = v.u;
  u += 0x7fffu + ((u >> 16) & 1u);
  return (unsigned short)(u >> 16);
}

// pack two f32 -> two bf16 (round-half-up): 2 adds + 1 v_perm
DEVI unsigned pk2bf(float a, float b) {
  union { float f; unsigned u; } x, y; x.f = a; y.f = b;
  return __builtin_amdgcn_perm(y.u + 0x8000u, x.u + 0x8000u, 0x07060302u);
}

DEVI f32x4 mfma16(bf16x8 a, bf16x8 b, f32x4 c) {
  return __builtin_amdgcn_mfma_f32_16x16x32_bf16(a, b, c, 0, 0, 0);
}

// async global->LDS, 16 B per lane; LDS dest = wave-uniform base + lane*16
DEVI void gld16(const unsigned short* g, unsigned short* l) {
  __builtin_amdgcn_global_load_lds(
      (const __attribute__((address_space(1))) unsigned int*)(uintptr_t)g,
      (__attribute__((address_space(3))) unsigned int*)(unsigned int)(uintptr_t)l,
      16, 0, 0);
}

// ---------------- fused fp32 -> bf16 convert (x, qkv_w, proj_w) -------------
__global__ __launch_bounds__(256) void cvt3_kernel(
    const float* __restrict__ x, const float* __restrict__ w1,
    const float* __restrict__ w2, unsigned short* __restrict__ ox,
    unsigned short* __restrict__ o1, unsigned short* __restrict__ o2) {
  int bid = blockIdx.x;
  const float* in; unsigned short* out; int base;
  if (bid < 8192)       { in = x;  out = ox; base = bid; }
  else if (bid < 11264) { in = w1; out = o1; base = bid - 8192; }
  else                  { in = w2; out = o2; base = bid - 11264; }
  int i = (base * 256 + threadIdx.x) * 4;
  float4 v = *(const float4*)(in + i);
  uint2 o; o.x = pk2bf(v.x, v.y); o.y = pk2bf(v.z, v.w);
  *(uint2*)(out + i) = o;
}

// ---------------- GEMM: C[M,N] = A[M,K] * Bw[N,K]^T + bias ----------------
// Computes C^T in registers (operand-swapped MFMA) so each lane's 4 acc
// values run along N -> vectorized stores.
template <int MODE>
__global__ __launch_bounds__(256) void gemm_bt(
    const unsigned short* __restrict__ A, const unsigned short* __restrict__ Bw,
    const float* __restrict__ bias, float* __restrict__ Cf,
    unsigned short* __restrict__ Qo, unsigned short* __restrict__ Ko,
    unsigned short* __restrict__ Vo, int M, int N, int K) {
  __shared__ unsigned short As[128 * 64];
  __shared__ unsigned short Bs[128 * 64];
  const int tid = threadIdx.x;
  const int lane = tid & 63;
  const int w = tid >> 6;
  const int wm = w & 1, wn = w >> 1;
  const int lr = lane & 15, lq = lane >> 4;
  const int m0 = blockIdx.y * 128;
  const int n0 = blockIdx.x * 128;
  const int l8r = lane >> 3;
  const int l8c = (lane & 7) << 3;

  f32x4 acc[4][4] = {};   // [mt][nt], each holds n = lq*4+r, m = lr

  for (int kt = 0; kt < K; kt += 64) {
    __syncthreads();
#pragma unroll
    for (int i = 0; i < 4; ++i) {
      int c = w * 4 + i;
      int row = c * 8 + l8r;
      gld16(A + (size_t)(m0 + row) * K + kt + l8c, &As[c * 8 * 64]);
      gld16(Bw + (size_t)(n0 + row) * K + kt + l8c, &Bs[c * 8 * 64]);
    }
    __syncthreads();
#pragma unroll
    for (int kk = 0; kk < 64; kk += 32) {
      bf16x8 af[4], bfr[4];
#pragma unroll
      for (int mt = 0; mt < 4; ++mt)
        af[mt] = *(const bf16x8*)(&As[(wm * 64 + mt * 16 + lr) * 64 + kk + lq * 8]);
#pragma unroll
      for (int nt = 0; nt < 4; ++nt)
        bfr[nt] = *(const bf16x8*)(&Bs[(wn * 64 + nt * 16 + lr) * 64 + kk + lq * 8]);
#pragma unroll
      for (int mt = 0; mt < 4; ++mt)
#pragma unroll
        for (int nt = 0; nt < 4; ++nt)
          acc[mt][nt] = mfma16(bfr[nt], af[mt], acc[mt][nt]);  // C^T
    }
  }

#pragma unroll
  for (int nt = 0; nt < 4; ++nt) {
    int n_base = n0 + wn * 64 + nt * 16 + lq * 4;   // 4 consecutive n
    float4 bv = *(const float4*)(bias + n_base);
#pragma unroll
    for (int mt = 0; mt < 4; ++mt) {
      int m_g = m0 + wm * 64 + mt * 16 + lr;
      float v0 = acc[mt][nt][0] + bv.x;
      float v1 = acc[mt][nt][1] + bv.y;
      float v2 = acc[mt][nt][2] + bv.z;
      float v3 = acc[mt][nt][3] + bv.w;
      if (MODE == 1) {
        float4 o; o.x = v0; o.y = v1; o.z = v2; o.w = v3;
        *(float4*)(Cf + (size_t)m_g * N + n_base) = o;
      } else {
        int which = n_base >> 10;            // uniform over the 4 n's
        int rem = n_base & 1023;
        int h = rem >> 6, d = rem & 63;
        int b = m_g >> 11, t = m_g & 2047;
        size_t idx = (((size_t)(b * 16 + h) * 2048) + t) * 64 + d;
        unsigned short* p = (which == 0) ? Qo : ((which == 1) ? Ko : Vo);
        uint2 o; o.x = pk2bf(v0, v1); o.y = pk2bf(v2, v3);
        *(uint2*)(p + idx) = o;
      }
    }
  }
}

// ------- flash attention (causal), S^T formulation, 128-row Q-tile/block ----
// Grid (16,16,4) = 1024 blocks; qt = 15-bx so heavy blocks dispatch first.
__global__ __launch_bounds__(256, 4) void attn_kernel(
    const unsigned short* __restrict__ Q, const unsigned short* __restrict__ K,
    const unsigned short* __restrict__ V, unsigned short* __restrict__ Y) {
  constexpr int T = 2048, HD = 64, H = 16;
  __shared__ unsigned short Kt[64 * 72];
  __shared__ unsigned short Vt[64 * 72];
  __shared__ unsigned short Pt[4][32 * 72];

  const int tid = threadIdx.x;
  const int lane = tid & 63;
  const int w = tid >> 6;
  const int lr = lane & 15, lq = lane >> 4;
  const int qt = 15 - (int)blockIdx.x;
  const int h = blockIdx.y;
  const int b = blockIdx.z;
  const size_t bh = (size_t)(b * H + h) * T * HD;
  const float SC = 0.125f * 1.44269504089f;   // 1/sqrt(64) * log2(e)

  const int q0 = qt * 128;
  const int nkv = 2 * qt + 2;
  const int qmin = q0 + w * 32;
  const int qmax = qmin + 31;

  const int krow = tid >> 3, kcb = (tid & 7) << 3;
  const int vrow = tid & 63, vc = (tid >> 6) * 8;

  float4 kr[2], vr[2];
  auto load_tile = [&](int jt) {
    const int c0 = jt * 64;
    kr[0] = *(const float4*)(K + bh + (size_t)(c0 + krow) * HD + kcb);
    kr[1] = *(const float4*)(K + bh + (size_t)(c0 + 32 + krow) * HD + kcb);
    vr[0] = *(const float4*)(V + bh + (size_t)(c0 + vrow) * HD + vc);
    vr[1] = *(const float4*)(V + bh + (size_t)(c0 + vrow) * HD + 32 + vc);
  };
  load_tile(0);

  // Q B-fragments
  bf16x8 qf[2][2];
#pragma unroll
  for (int qs = 0; qs < 2; ++qs)
#pragma unroll
    for (int kb = 0; kb < 2; ++kb)
      qf[qs][kb] = *(const bf16x8*)(Q + bh + (size_t)(qmin + qs * 16 + lr) * HD +
                                    kb * 32 + lq * 8);

  f32x4 o[2][4] = {};
  float mi[2] = {-INFINITY, -INFINITY}, li[2] = {0.f, 0.f};

  for (int jt = 0; jt < nkv; ++jt) {
    const int c0 = jt * 64;
    __syncthreads();
    *(float4*)(&Kt[krow * 72 + kcb]) = kr[0];
    *(float4*)(&Kt[(32 + krow) * 72 + kcb]) = kr[1];
    {
      const unsigned short* vp0 = (const unsigned short*)&vr[0];
      const unsigned short* vp1 = (const unsigned short*)&vr[1];
#pragma unroll
      for (int j = 0; j < 8; ++j) Vt[(vc + j) * 72 + vrow] = vp0[j];
#pragma unroll
      for (int j = 0; j < 8; ++j) Vt[(32 + vc + j) * 72 + vrow] = vp1[j];
    }
    __syncthreads();
    if (jt + 1 < nkv) load_tile(jt + 1);

    if (c0 > qmax) continue;           // wave-uniform: tile fully masked

    // S^T = K Q^T : lane holds q = lr (per qs), kv = nt*16 + lq*4 + r (raw, unscaled)
    f32x4 s[2][4];
#pragma unroll
    for (int nt = 0; nt < 4; ++nt) {
      bf16x8 kf0 = *(const bf16x8*)(&Kt[(nt * 16 + lr) * 72 + lq * 8]);
      bf16x8 kf1 = *(const bf16x8*)(&Kt[(nt * 16 + lr) * 72 + 32 + lq * 8]);
#pragma unroll
      for (int qs = 0; qs < 2; ++qs) {
        f32x4 z = {};
        z = mfma16(kf0, qf[qs][0], z);
        s[qs][nt] = mfma16(kf1, qf[qs][1], z);
      }
    }
    // causal mask on raw scores (only near the diagonal; wave-uniform branch)
    if (c0 + 63 > qmin) {
#pragma unroll
      for (int qs = 0; qs < 2; ++qs) {
        int qg = qmin + qs * 16 + lr;
#pragma unroll
        for (int nt = 0; nt < 4; ++nt)
#pragma unroll
          for (int r = 0; r < 4; ++r) {
            int kvg = c0 + nt * 16 + lq * 4 + r;
            if (kvg > qg) s[qs][nt][r] = -INFINITY;
          }
      }
    }
    // online softmax in log2 domain; SC folded into exp via fma
#pragma unroll
    for (int qs = 0; qs < 2; ++qs) {
      float mx = -INFINITY;
#pragma unroll
      for (int nt = 0; nt < 4; ++nt) {
        float a = fmaxf(fmaxf(s[qs][nt][0], s[qs][nt][1]),
                        fmaxf(s[qs][nt][2], s[qs][nt][3]));
        mx = fmaxf(mx, a);
      }
      mx = fmaxf(mx, __shfl_xor(mx, 16));
      mx = fmaxf(mx, __shfl_xor(mx, 32));
      float mnew = fmaxf(mi[qs], mx * SC);
      float alpha = __builtin_amdgcn_exp2f(mi[qs] - mnew);
      mi[qs] = mnew;
      float rs = 0.f;
#pragma unroll
      for (int nt = 0; nt < 4; ++nt) {
        float p0 = __builtin_amdgcn_exp2f(__builtin_fmaf(s[qs][nt][0], SC, -mnew));
        float p1 = __builtin_amdgcn_exp2f(__builtin_fmaf(s[qs][nt][1], SC, -mnew));
        float p2 = __builtin_amdgcn_exp2f(__builtin_fmaf(s[qs][nt][2], SC, -mnew));
        float p3 = __builtin_amdgcn_exp2f(__builtin_fmaf(s[qs][nt][3], SC, -mnew));
        rs += (p0 + p1) + (p2 + p3);
        uint2 pk; pk.x = pk2bf(p0, p1); pk.y = pk2bf(p2, p3);
        *(uint2*)(&Pt[w][(qs * 16 + lr) * 72 + nt * 16 + lq * 4]) = pk;
      }
      rs += __shfl_xor(rs, 16);
      rs += __shfl_xor(rs, 32);
      li[qs] = li[qs] * alpha + rs;
#pragma unroll
      for (int nt = 0; nt < 4; ++nt)
#pragma unroll
        for (int r = 0; r < 4; ++r) o[qs][nt][r] *= alpha;
    }
    // O^T += V^T P^T
    bf16x8 pf[2][2];
#pragma unroll
    for (int qs = 0; qs < 2; ++qs)
#pragma unroll
      for (int kb = 0; kb < 2; ++kb)
        pf[qs][kb] = *(const bf16x8*)(&Pt[w][(qs * 16 + lr) * 72 + kb * 32 + lq * 8]);
#pragma unroll
    for (int nt = 0; nt < 4; ++nt) {
      bf16x8 vf0 = *(const bf16x8*)(&Vt[(nt * 16 + lr) * 72 + lq * 8]);
      bf16x8 vf1 = *(const bf16x8*)(&Vt[(nt * 16 + lr) * 72 + 32 + lq * 8]);
#pragma unroll
      for (int qs = 0; qs < 2; ++qs) {
        o[qs][nt] = mfma16(vf0, pf[qs][0], o[qs][nt]);
        o[qs][nt] = mfma16(vf1, pf[qs][1], o[qs][nt]);
      }
    }
  }

  // epilogue: Y[b, t=q, h*64 + d]; lane holds q = lr, d = nt*16 + lq*4 + r
#pragma unroll
  for (int qs = 0; qs < 2; ++qs) {
    float inv = 1.f / li[qs];
    int t_g = qmin + qs * 16 + lr;
#pragma unroll
    for (int nt = 0; nt < 4; ++nt) {
      uint2 yv;
      yv.x = pk2bf(o[qs][nt][0] * inv, o[qs][nt][1] * inv);
      yv.y = pk2bf(o[qs][nt][2] * inv, o[qs][nt][3] * inv);
      *(uint2*)(Y + ((size_t)(b * T + t_g)) * 1024 + h * 64 + nt * 16 + lq * 4) = yv;
    }
  }
}

// ---------------- launch ----------------
extern "C" void kernel_launch(void* const* d_in, const int* in_sizes, int n_in,
                              void* d_out, int out_size, void* d_ws, size_t ws_size,
                              hipStream_t stream) {
  const float* x = (const float*)d_in[0];
  const float* qkv_w = (const float*)d_in[1];
  const float* qkv_b = (const float*)d_in[2];
  const float* proj_w = (const float*)d_in[3];
  const float* proj_b = (const float*)d_in[4];
  float* out = (float*)d_out;

  unsigned short* ws = (unsigned short*)d_ws;
  unsigned short* xb = ws;                     // 8388608
  unsigned short* wqkv = xb + 8388608;         // 3145728
  unsigned short* wproj = wqkv + 3145728;      // 1048576
  unsigned short* Qb = wproj + 1048576;        // 8388608 [B,H,T,hd]
  unsigned short* Kb = Qb + 8388608;
  unsigned short* Vb = Kb + 8388608;
  unsigned short* Yb = Vb + 8388608;           // [B*T, C]

  cvt3_kernel<<<12288, 256, 0, stream>>>(x, qkv_w, proj_w, xb, wqkv, wproj);

  gemm_bt<0><<<dim3(24, 64), 256, 0, stream>>>(xb, wqkv, qkv_b, nullptr, Qb, Kb, Vb,
                                               8192, 3072, 1024);
  attn_kernel<<<dim3(16, 16, 4), 256, 0, stream>>>(Qb, Kb, Vb, Yb);
  gemm_bt<1><<<dim3(8, 64), 256, 0, stream>>>(Yb, wproj, proj_b, out, nullptr, nullptr,
                                              nullptr, 8192, 1024, 1024);
}

// Round 5
// 298.097 us; speedup vs baseline: 1.1548x; 1.1548x over previous
//
#include <hip/hip_runtime.h>
#include <stdint.h>
#include <math.h>

#define DEVI __device__ __forceinline__

typedef __attribute__((ext_vector_type(8))) short bf16x8;
typedef __attribute__((ext_vector_type(4))) float f32x4;

// pack two f32 -> two bf16 (round-half-up): 2 adds + 1 v_perm
DEVI unsigned pk2bf(float a, float b) {
  union { float f; unsigned u; } x, y; x.f = a; y.f = b;
  return __builtin_amdgcn_perm(y.u + 0x8000u, x.u + 0x8000u, 0x07060302u);
}

DEVI f32x4 mfma16(bf16x8 a, bf16x8 b, f32x4 c) {
  return __builtin_amdgcn_mfma_f32_16x16x32_bf16(a, b, c, 0, 0, 0);
}

// async global->LDS, 16 B per lane; LDS dest = wave-uniform base + lane*16
DEVI void gld16(const unsigned short* g, unsigned short* l) {
  __builtin_amdgcn_global_load_lds(
      (const __attribute__((address_space(1))) unsigned int*)(uintptr_t)g,
      (__attribute__((address_space(3))) unsigned int*)(unsigned int)(uintptr_t)l,
      16, 0, 0);
}

// ---------------- fused fp32 -> bf16 convert (x, qkv_w, proj_w) -------------
__global__ __launch_bounds__(256) void cvt3_kernel(
    const float* __restrict__ x, const float* __restrict__ w1,
    const float* __restrict__ w2, unsigned short* __restrict__ ox,
    unsigned short* __restrict__ o1, unsigned short* __restrict__ o2) {
  int bid = blockIdx.x;
  const float* in; unsigned short* out; int base;
  if (bid < 8192)       { in = x;  out = ox; base = bid; }
  else if (bid < 11264) { in = w1; out = o1; base = bid - 8192; }
  else                  { in = w2; out = o2; base = bid - 11264; }
  int i = (base * 256 + threadIdx.x) * 4;
  float4 v = *(const float4*)(in + i);
  uint2 o; o.x = pk2bf(v.x, v.y); o.y = pk2bf(v.z, v.w);
  *(uint2*)(out + i) = o;
}

// ---------------- GEMM: C[M,N] = A[M,K] * Bw[N,K]^T + bias ----------------
// Computes C^T in registers (operand-swapped MFMA) -> vectorized stores.
template <int MODE>
__global__ __launch_bounds__(256) void gemm_bt(
    const unsigned short* __restrict__ A, const unsigned short* __restrict__ Bw,
    const float* __restrict__ bias, float* __restrict__ Cf,
    unsigned short* __restrict__ Qo, unsigned short* __restrict__ Ko,
    unsigned short* __restrict__ Vo, int M, int N, int K) {
  __shared__ unsigned short As[128 * 64];
  __shared__ unsigned short Bs[128 * 64];
  const int tid = threadIdx.x;
  const int lane = tid & 63;
  const int w = tid >> 6;
  const int wm = w & 1, wn = w >> 1;
  const int lr = lane & 15, lq = lane >> 4;
  const int m0 = blockIdx.y * 128;
  const int n0 = blockIdx.x * 128;
  const int l8r = lane >> 3;
  const int l8c = (lane & 7) << 3;

  f32x4 acc[4][4] = {};   // [mt][nt], lane holds n = lq*4+r, m = lr

  for (int kt = 0; kt < K; kt += 64) {
    __syncthreads();
#pragma unroll
    for (int i = 0; i < 4; ++i) {
      int c = w * 4 + i;
      int row = c * 8 + l8r;
      gld16(A + (size_t)(m0 + row) * K + kt + l8c, &As[c * 8 * 64]);
      gld16(Bw + (size_t)(n0 + row) * K + kt + l8c, &Bs[c * 8 * 64]);
    }
    __syncthreads();
#pragma unroll
    for (int kk = 0; kk < 64; kk += 32) {
      bf16x8 af[4], bfr[4];
#pragma unroll
      for (int mt = 0; mt < 4; ++mt)
        af[mt] = *(const bf16x8*)(&As[(wm * 64 + mt * 16 + lr) * 64 + kk + lq * 8]);
#pragma unroll
      for (int nt = 0; nt < 4; ++nt)
        bfr[nt] = *(const bf16x8*)(&Bs[(wn * 64 + nt * 16 + lr) * 64 + kk + lq * 8]);
#pragma unroll
      for (int mt = 0; mt < 4; ++mt)
#pragma unroll
        for (int nt = 0; nt < 4; ++nt)
          acc[mt][nt] = mfma16(bfr[nt], af[mt], acc[mt][nt]);  // C^T
    }
  }

#pragma unroll
  for (int nt = 0; nt < 4; ++nt) {
    int n_base = n0 + wn * 64 + nt * 16 + lq * 4;   // 4 consecutive n
    float4 bv = *(const float4*)(bias + n_base);
#pragma unroll
    for (int mt = 0; mt < 4; ++mt) {
      int m_g = m0 + wm * 64 + mt * 16 + lr;
      float v0 = acc[mt][nt][0] + bv.x;
      float v1 = acc[mt][nt][1] + bv.y;
      float v2 = acc[mt][nt][2] + bv.z;
      float v3 = acc[mt][nt][3] + bv.w;
      if (MODE == 1) {
        float4 o; o.x = v0; o.y = v1; o.z = v2; o.w = v3;
        *(float4*)(Cf + (size_t)m_g * N + n_base) = o;
      } else {
        int which = n_base >> 10;            // uniform over the 4 n's
        int rem = n_base & 1023;
        int h = rem >> 6, d = rem & 63;
        int b = m_g >> 11, t = m_g & 2047;
        size_t idx = (((size_t)(b * 16 + h) * 2048) + t) * 64 + d;
        unsigned short* p = (which == 0) ? Qo : ((which == 1) ? Ko : Vo);
        uint2 o; o.x = pk2bf(v0, v1); o.y = pk2bf(v2, v3);
        *(uint2*)(p + idx) = o;
      }
    }
  }
}

// ------- flash attention (causal), S^T formulation, 128-row Q-tiles -------
// Block: 4 waves x 32 q-rows; paired q-tiles (pair, 15-pair) -> uniform 34
// KV-iterations per block. Grid 512 blocks, 2 blocks/CU, no VGPR squeeze.
__global__ __launch_bounds__(256, 2) void attn_kernel(
    const unsigned short* __restrict__ Q, const unsigned short* __restrict__ K,
    const unsigned short* __restrict__ V, unsigned short* __restrict__ Y) {
  constexpr int T = 2048, HD = 64, H = 16;
  __shared__ unsigned short Kt[64 * 72];
  __shared__ unsigned short Vt[64 * 72];
  __shared__ unsigned short Pt[4][32 * 72];

  const int tid = threadIdx.x;
  const int lane = tid & 63;
  const int w = tid >> 6;
  const int lr = lane & 15, lq = lane >> 4;
  const int pair = blockIdx.x;  // 0..7
  const int h = blockIdx.y;
  const int b = blockIdx.z;
  const size_t bh = (size_t)(b * H + h) * T * HD;
  const float SC = 0.125f * 1.44269504089f;   // 1/sqrt(64) * log2(e)

  const int krow = tid >> 3, kcb = (tid & 7) << 3;
  const int vrow = tid & 63, vc = (tid >> 6) * 8;

  float4 kr[2], vr[2];
  auto load_tile = [&](int jt) {
    const int c0 = jt * 64;
    kr[0] = *(const float4*)(K + bh + (size_t)(c0 + krow) * HD + kcb);
    kr[1] = *(const float4*)(K + bh + (size_t)(c0 + 32 + krow) * HD + kcb);
    vr[0] = *(const float4*)(V + bh + (size_t)(c0 + vrow) * HD + vc);
    vr[1] = *(const float4*)(V + bh + (size_t)(c0 + vrow) * HD + 32 + vc);
  };
  load_tile(0);

  for (int phase = 0; phase < 2; ++phase) {
    const int qt = phase ? (15 - pair) : pair;
    const int q0 = qt * 128;
    const int nkv = 2 * qt + 2;
    const int qmin = q0 + w * 32;
    const int qmax = qmin + 31;

    // Q B-fragments (q = lr within each 16-row set)
    bf16x8 qf[2][2];
#pragma unroll
    for (int qs = 0; qs < 2; ++qs)
#pragma unroll
      for (int kb = 0; kb < 2; ++kb)
        qf[qs][kb] = *(const bf16x8*)(Q + bh + (size_t)(qmin + qs * 16 + lr) * HD +
                                      kb * 32 + lq * 8);

    f32x4 o[2][4] = {};
    float mi[2] = {-INFINITY, -INFINITY}, li[2] = {0.f, 0.f};

    for (int jt = 0; jt < nkv; ++jt) {
      const int c0 = jt * 64;
      __syncthreads();
      *(float4*)(&Kt[krow * 72 + kcb]) = kr[0];
      *(float4*)(&Kt[(32 + krow) * 72 + kcb]) = kr[1];
      {
        const unsigned short* vp0 = (const unsigned short*)&vr[0];
        const unsigned short* vp1 = (const unsigned short*)&vr[1];
#pragma unroll
        for (int j = 0; j < 8; ++j) Vt[(vc + j) * 72 + vrow] = vp0[j];
#pragma unroll
        for (int j = 0; j < 8; ++j) Vt[(32 + vc + j) * 72 + vrow] = vp1[j];
      }
      __syncthreads();
      // prefetch next tile (or phase-1's tile 0 at the seam)
      if (jt + 1 < nkv) load_tile(jt + 1);
      else if (phase == 0) load_tile(0);

      if (c0 > qmax) continue;           // wave-uniform: tile fully masked

      // S^T = K Q^T : lane holds q = lr (per qs), kv = nt*16+lq*4+r (raw)
      f32x4 s[2][4];
#pragma unroll
      for (int nt = 0; nt < 4; ++nt) {
        bf16x8 kf0 = *(const bf16x8*)(&Kt[(nt * 16 + lr) * 72 + lq * 8]);
        bf16x8 kf1 = *(const bf16x8*)(&Kt[(nt * 16 + lr) * 72 + 32 + lq * 8]);
#pragma unroll
        for (int qs = 0; qs < 2; ++qs) {
          f32x4 z = {};
          z = mfma16(kf0, qf[qs][0], z);
          s[qs][nt] = mfma16(kf1, qf[qs][1], z);
        }
      }
      // causal mask on raw scores (only near the diagonal; wave-uniform)
      if (c0 + 63 > qmin) {
#pragma unroll
        for (int qs = 0; qs < 2; ++qs) {
          int qg = qmin + qs * 16 + lr;
#pragma unroll
          for (int nt = 0; nt < 4; ++nt)
#pragma unroll
            for (int r = 0; r < 4; ++r) {
              int kvg = c0 + nt * 16 + lq * 4 + r;
              if (kvg > qg) s[qs][nt][r] = -INFINITY;
            }
        }
      }
      // online softmax in log2 domain; SC folded into exp via fma
#pragma unroll
      for (int qs = 0; qs < 2; ++qs) {
        float mx = -INFINITY;
#pragma unroll
        for (int nt = 0; nt < 4; ++nt) {
          float a = fmaxf(fmaxf(s[qs][nt][0], s[qs][nt][1]),
                          fmaxf(s[qs][nt][2], s[qs][nt][3]));
          mx = fmaxf(mx, a);
        }
        mx = fmaxf(mx, __shfl_xor(mx, 16));
        mx = fmaxf(mx, __shfl_xor(mx, 32));
        float mnew = fmaxf(mi[qs], mx * SC);
        float alpha = __builtin_amdgcn_exp2f(mi[qs] - mnew);
        mi[qs] = mnew;
        float rs = 0.f;
#pragma unroll
        for (int nt = 0; nt < 4; ++nt) {
          float p0 = __builtin_amdgcn_exp2f(__builtin_fmaf(s[qs][nt][0], SC, -mnew));
          float p1 = __builtin_amdgcn_exp2f(__builtin_fmaf(s[qs][nt][1], SC, -mnew));
          float p2 = __builtin_amdgcn_exp2f(__builtin_fmaf(s[qs][nt][2], SC, -mnew));
          float p3 = __builtin_amdgcn_exp2f(__builtin_fmaf(s[qs][nt][3], SC, -mnew));
          rs += (p0 + p1) + (p2 + p3);
          uint2 pk; pk.x = pk2bf(p0, p1); pk.y = pk2bf(p2, p3);
          *(uint2*)(&Pt[w][(qs * 16 + lr) * 72 + nt * 16 + lq * 4]) = pk;
        }
        rs += __shfl_xor(rs, 16);
        rs += __shfl_xor(rs, 32);
        li[qs] = li[qs] * alpha + rs;
#pragma unroll
        for (int nt = 0; nt < 4; ++nt)
#pragma unroll
          for (int r = 0; r < 4; ++r) o[qs][nt][r] *= alpha;
      }
      // O^T += V^T P^T
      bf16x8 pf[2][2];
#pragma unroll
      for (int qs = 0; qs < 2; ++qs)
#pragma unroll
        for (int kb = 0; kb < 2; ++kb)
          pf[qs][kb] = *(const bf16x8*)(&Pt[w][(qs * 16 + lr) * 72 + kb * 32 + lq * 8]);
#pragma unroll
      for (int nt = 0; nt < 4; ++nt) {
        bf16x8 vf0 = *(const bf16x8*)(&Vt[(nt * 16 + lr) * 72 + lq * 8]);
        bf16x8 vf1 = *(const bf16x8*)(&Vt[(nt * 16 + lr) * 72 + 32 + lq * 8]);
#pragma unroll
        for (int qs = 0; qs < 2; ++qs) {
          o[qs][nt] = mfma16(vf0, pf[qs][0], o[qs][nt]);
          o[qs][nt] = mfma16(vf1, pf[qs][1], o[qs][nt]);
        }
      }
    }

    // epilogue: Y[b, t=q, h*64+d]; lane holds q = lr, d = nt*16 + lq*4 + r
#pragma unroll
    for (int qs = 0; qs < 2; ++qs) {
      float inv = 1.f / li[qs];
      int t_g = qmin + qs * 16 + lr;
#pragma unroll
      for (int nt = 0; nt < 4; ++nt) {
        uint2 yv;
        yv.x = pk2bf(o[qs][nt][0] * inv, o[qs][nt][1] * inv);
        yv.y = pk2bf(o[qs][nt][2] * inv, o[qs][nt][3] * inv);
        *(uint2*)(Y + ((size_t)(b * T + t_g)) * 1024 + h * 64 + nt * 16 + lq * 4) = yv;
      }
    }
  }
}

// ---------------- launch ----------------
extern "C" void kernel_launch(void* const* d_in, const int* in_sizes, int n_in,
                              void* d_out, int out_size, void* d_ws, size_t ws_size,
                              hipStream_t stream) {
  const float* x = (const float*)d_in[0];
  const float* qkv_w = (const float*)d_in[1];
  const float* qkv_b = (const float*)d_in[2];
  const float* proj_w = (const float*)d_in[3];
  const float* proj_b = (const float*)d_in[4];
  float* out = (float*)d_out;

  unsigned short* ws = (unsigned short*)d_ws;
  unsigned short* xb = ws;                     // 8388608
  unsigned short* wqkv = xb + 8388608;         // 3145728
  unsigned short* wproj = wqkv + 3145728;      // 1048576
  unsigned short* Qb = wproj + 1048576;        // 8388608 [B,H,T,hd]
  unsigned short* Kb = Qb + 8388608;
  unsigned short* Vb = Kb + 8388608;
  unsigned short* Yb = Vb + 8388608;           // [B*T, C]

  cvt3_kernel<<<12288, 256, 0, stream>>>(x, qkv_w, proj_w, xb, wqkv, wproj);

  gemm_bt<0><<<dim3(24, 64), 256, 0, stream>>>(xb, wqkv, qkv_b, nullptr, Qb, Kb, Vb,
                                               8192, 3072, 1024);
  attn_kernel<<<dim3(8, 16, 4), 256, 0, stream>>>(Qb, Kb, Vb, Yb);
  gemm_bt<1><<<dim3(8, 64), 256, 0, stream>>>(Yb, wproj, proj_b, out, nullptr, nullptr,
                                              nullptr, 8192, 1024, 1024);
}